// Round 1
// baseline (286.260 us; speedup 1.0000x reference)
//
#include <hip/hip_runtime.h>
#include <math.h>

#define N_NODES 16384
#define N_EDGES 262144
#define IN_DIM  512
#define HID     256
#define HEADS   4
#define NBATCH  64
#define ACTIONS 32
#define NEG_SLOPE 0.2f

typedef __attribute__((ext_vector_type(8))) short short8;
typedef __attribute__((ext_vector_type(4))) float f32x4;

__device__ __forceinline__ float lrelu(float v) { return v > 0.f ? v : NEG_SLOPE * v; }

__device__ __forceinline__ unsigned short bf16_rne(float f) {
    union { float f; unsigned int u; } x; x.f = f;
    unsigned int u = x.u;
    unsigned int r = (u + 0x7FFFu + ((u >> 16) & 1u)) >> 16;
    return (unsigned short)r;
}

__device__ __forceinline__ float bf16_to_f32(unsigned short s) {
    union { unsigned int u; float f; } x; x.u = (unsigned int)s << 16;
    return x.f;
}

__device__ __forceinline__ float blo(unsigned int u) {
    union { unsigned int u; float f; } x; x.u = u << 16; return x.f;
}
__device__ __forceinline__ float bhi(unsigned int u) {
    union { unsigned int u; float f; } x; x.u = u & 0xFFFF0000u; return x.f;
}
__device__ __forceinline__ unsigned int pack_bf16x2(float a, float b) {
    return (unsigned int)bf16_rne(a) | ((unsigned int)bf16_rne(b) << 16);
}

__device__ __forceinline__ void async_copy16(const unsigned short* g, unsigned short* l) {
    __builtin_amdgcn_global_load_lds(
        (const __attribute__((address_space(1))) unsigned int*)g,
        (__attribute__((address_space(3))) unsigned int*)l, 16, 0, 0);
}

// ---------------------------------------------------------------- fused setup (+ deg count; zeroing moved to hipMemsetAsync)
#define NB_WLR  1024
#define NB_WSTK 1024
#define NB_WATT 8
#define NB_DEG  1024
#define NB_SETUP (NB_WLR + NB_WSTK + NB_WATT + NB_DEG)

__global__ __launch_bounds__(256) void setup_kernel(
        const float* __restrict__ wl, const float* __restrict__ wr, unsigned short* __restrict__ bt1,
        const float* __restrict__ gat_w, unsigned short* __restrict__ bt2,
        const float* __restrict__ att_src, const float* __restrict__ att_dst, float* __restrict__ watt,
        const int* __restrict__ ei, int* __restrict__ deg) {
    int bid = blockIdx.x, tid = threadIdx.x;
    if (bid < NB_WLR) {
        int idx = bid * 256 + tid;
        int j = idx >> 9;
        int k = idx & 511;
        float v = (j < HID) ? wl[k * HID + j] : wr[k * HID + (j - HID)];
        bt1[idx] = bf16_rne(v);
    } else if (bid < NB_WLR + NB_WSTK) {
        int idx = (bid - NB_WLR) * 256 + tid;
        int c = idx >> 10;
        int r = idx & 1023;
        int h = r >> 8;
        int k = r & 255;
        bt2[idx] = bf16_rne(gat_w[(size_t)k * (HEADS * HID) + h * HID + c]);
    } else if (bid < NB_WLR + NB_WSTK + NB_WATT) {
        int j = bid - NB_WLR - NB_WSTK;
        int c = tid;
        int hh = j & 3;
        const float* att = (j < 4) ? (att_src + hh * HID) : (att_dst + hh * HID);
        float s = 0.f;
        for (int cc = 0; cc < HID; cc++)
            s += gat_w[(size_t)c * (HEADS * HID) + hh * HID + cc] * att[cc];
        watt[j * HID + c] = s;
    } else {
        int e = (bid - NB_WLR - NB_WSTK - NB_WATT) * 256 + tid;
        if (e < N_EDGES) atomicAdd(&deg[ei[N_EDGES + e]], 1);
    }
}

// ---------------------------------------------------------------- CSR scan
__global__ __launch_bounds__(256) void scan_kernel(const int* __restrict__ deg,
                                                   int* __restrict__ row_start,
                                                   int* __restrict__ pos) {
    int t = threadIdx.x;
    int lane = t & 63, wv = t >> 6;
    int base = t * 64;
    int4 buf[16];
    int sum = 0;
#pragma unroll
    for (int i = 0; i < 16; i++) {
        buf[i] = ((const int4*)(deg + base))[i];
        sum += buf[i].x + buf[i].y + buf[i].z + buf[i].w;
    }
    int v = sum;
#pragma unroll
    for (int off = 1; off < 64; off <<= 1) {
        int u = __shfl_up(v, off);
        if (lane >= off) v += u;
    }
    __shared__ int wsum[4];
    if (lane == 63) wsum[wv] = v;
    __syncthreads();
    int wbase = 0;
    for (int w0 = 0; w0 < wv; w0++) wbase += wsum[w0];
    int run = wbase + v - sum;
#pragma unroll
    for (int i = 0; i < 16; i++) {
        int4 b = buf[i];
        int4 o;
        o.x = run; run += b.x;
        o.y = run; run += b.y;
        o.z = run; run += b.z;
        o.w = run; run += b.w;
        ((int4*)(row_start + base))[i] = o;
        ((int4*)(pos + base))[i] = o;
    }
    if (t == 255) row_start[N_NODES] = run;
}

// ---------------------------------------------------------------- GEMM1 (even y) + CSR fill (odd y) merged
#define BK 32

__global__ __launch_bounds__(256) void gemm1_fill_kernel(const float* __restrict__ X,
                                                         const unsigned short* __restrict__ Bt,
                                                         unsigned short* __restrict__ Cb,
                                                         const int* __restrict__ ei,
                                                         int* __restrict__ pos,
                                                         int* __restrict__ col,
                                                         int Nn, int K) {
    __shared__ __align__(16) unsigned short As[2][64 * BK];
    __shared__ __align__(16) unsigned short Bs[2][128 * BK];

    int tid  = threadIdx.x;

    if (blockIdx.y & 1) {
        // ---- fill role: 1024 blocks interleaved with gemm blocks
        int fid = (blockIdx.y >> 1) * 4 + blockIdx.x;
        int e = fid * 256 + tid;
        if (e < N_EDGES) {
            int s = ei[e];
            int d = ei[N_EDGES + e];
            int p = atomicAdd(&pos[d], 1);
            col[p] = s;
        }
        return;
    }

    int wv   = tid >> 6;
    int lane = tid & 63;
    int m0 = (blockIdx.y >> 1) * 64;
    int n0 = blockIdx.x * 128;
    int wm = (wv & 1) * 32;
    int wn = (wv >> 1) * 64;

    int srow = tid >> 2;            // 0..63
    int scol = (tid & 3) * 8;       // 0,8,16,24
    const float*          Xg  = X  + (size_t)(m0 + srow) * K + scol;
    const unsigned short* Bg0 = Bt + (size_t)(n0 + srow) * K + scol;
    const unsigned short* Bg1 = Bt + (size_t)(n0 + 64 + srow) * K + scol;

    int fr = lane & 15;
    int fk = (lane >> 4) * 8;
    f32x4 acc[2][4] = {};

    for (int kt = 0; kt < K; kt += 2 * BK) {
#pragma unroll
        for (int s = 0; s < 2; s++) {
            int ko = kt + s * BK;
            async_copy16(Bg0 + ko, &Bs[s][wv * 512]);
            async_copy16(Bg1 + ko, &Bs[s][2048 + wv * 512]);
            float4 a0 = *(const float4*)(Xg + ko);
            float4 a1 = *(const float4*)(Xg + ko + 4);
            short8 p;
            p[0] = (short)bf16_rne(a0.x); p[1] = (short)bf16_rne(a0.y);
            p[2] = (short)bf16_rne(a0.z); p[3] = (short)bf16_rne(a0.w);
            p[4] = (short)bf16_rne(a1.x); p[5] = (short)bf16_rne(a1.y);
            p[6] = (short)bf16_rne(a1.z); p[7] = (short)bf16_rne(a1.w);
            *(short8*)&As[s][srow * BK + scol] = p;
        }
        __syncthreads();

#pragma unroll
        for (int s = 0; s < 2; s++) {
            short8 af[2], bf[4];
#pragma unroll
            for (int mi = 0; mi < 2; mi++)
                af[mi] = *(const short8*)&As[s][(wm + mi * 16 + fr) * BK + fk];
#pragma unroll
            for (int ni = 0; ni < 4; ni++)
                bf[ni] = *(const short8*)&Bs[s][(wn + ni * 16 + fr) * BK + fk];
#pragma unroll
            for (int mi = 0; mi < 2; mi++)
#pragma unroll
                for (int ni = 0; ni < 4; ni++)
                    acc[mi][ni] = __builtin_amdgcn_mfma_f32_16x16x32_bf16(af[mi], bf[ni], acc[mi][ni], 0, 0, 0);
        }
        __syncthreads();
    }

    int cr = (lane >> 4) * 4;
    int cc = lane & 15;
#pragma unroll
    for (int mi = 0; mi < 2; mi++) {
#pragma unroll
        for (int ni = 0; ni < 4; ni++) {
            int gc = n0 + wn + ni * 16 + cc;
#pragma unroll
            for (int r = 0; r < 4; r++) {
                int gr = m0 + wm + mi * 16 + cr + r;
                Cb[(size_t)gr * Nn + gc] = bf16_rne(acc[mi][ni][r]);
            }
        }
    }
}

// ---------------------------------------------------------------- SAGE aggregation, column-split (pass = blockIdx.y)
// Per pass: 128 cols -> gathered working set 16384*256B = 4.2MB (~L2-resident per XCD)
__global__ __launch_bounds__(256) void sage_pass_kernel(const unsigned short* __restrict__ xlr,
                                                        const int* __restrict__ row_start,
                                                        const int* __restrict__ col,
                                                        const float* __restrict__ b_l,
                                                        const float* __restrict__ watt,
                                                        unsigned short* __restrict__ hb,
                                                        float* __restrict__ a_att) {
    __shared__ float watt_s[8 * 128];
    int p = blockIdx.y;
    for (int i = threadIdx.x; i < 8 * 128; i += 256) {
        int j = i >> 7, cc = i & 127;
        watt_s[i] = watt[j * HID + p * 128 + cc];
    }
    __syncthreads();

    int wave = threadIdx.x >> 6;
    int lane = threadIdx.x & 63;
    int n = blockIdx.x * 4 + wave;
    int start = row_start[n], end = row_start[n + 1];
    int lc = lane * 2;
    int cb = p * 128 + lc;                      // 2 columns per lane
    const unsigned short* xg = xlr + cb;

    float ax = 0.f, ay = 0.f;
    int e = start;
    for (; e + 4 <= end; e += 4) {
        int s0 = col[e], s1 = col[e + 1], s2 = col[e + 2], s3 = col[e + 3];
        unsigned int u0 = *(const unsigned int*)(xg + (size_t)s0 * IN_DIM);
        unsigned int u1 = *(const unsigned int*)(xg + (size_t)s1 * IN_DIM);
        unsigned int u2 = *(const unsigned int*)(xg + (size_t)s2 * IN_DIM);
        unsigned int u3 = *(const unsigned int*)(xg + (size_t)s3 * IN_DIM);
        ax += (blo(u0) + blo(u1)) + (blo(u2) + blo(u3));
        ay += (bhi(u0) + bhi(u1)) + (bhi(u2) + bhi(u3));
    }
    for (; e < end; e++) {
        unsigned int u = *(const unsigned int*)(xg + (size_t)col[e] * IN_DIM);
        ax += blo(u); ay += bhi(u);
    }

    float inv = 1.f / (float)max(end - start, 1);
    unsigned int ur = *(const unsigned int*)(xlr + (size_t)n * IN_DIM + HID + cb);
    float hx = fmaxf(fmaf(ax, inv, b_l[cb] + blo(ur)), 0.f);
    float hy = fmaxf(fmaf(ay, inv, b_l[cb + 1] + bhi(ur)), 0.f);
    *(unsigned int*)(hb + (size_t)n * HID + cb) = pack_bf16x2(hx, hy);

    float pj[8];
#pragma unroll
    for (int j = 0; j < 8; j++)
        pj[j] = hx * watt_s[j * 128 + lc] + hy * watt_s[j * 128 + lc + 1];
#pragma unroll
    for (int off = 32; off; off >>= 1)
#pragma unroll
        for (int j = 0; j < 8; j++) pj[j] += __shfl_down(pj[j], off);
    if (lane == 0) {
#pragma unroll
        for (int j = 0; j < 8; j++) atomicAdd(&a_att[n * 8 + j], pj[j]);
    }
}

// ---------------------------------------------------------------- GAT edge weights (gathers only a_att: 512KB, L2-resident)
__global__ __launch_bounds__(256) void gat_w_kernel(const float* __restrict__ a_att,
                                                    const int* __restrict__ row_start,
                                                    const int* __restrict__ col,
                                                    float* __restrict__ ew,
                                                    float* __restrict__ inv_att) {
    int wave = threadIdx.x >> 6;
    int lane = threadIdx.x & 63;
    int n = blockIdx.x * 4 + wave;
    int start = row_start[n], end = row_start[n + 1];

    float4 an = *(const float4*)(a_att + n * 8);
    float4 ad = *(const float4*)(a_att + n * 8 + 4);
    float sl0 = lrelu(an.x + ad.x), sl1 = lrelu(an.y + ad.y);
    float sl2 = lrelu(an.z + ad.z), sl3 = lrelu(an.w + ad.w);
    float m0 = fmaxf(sl0, 0.f), m1 = fmaxf(sl1, 0.f);
    float m2 = fmaxf(sl2, 0.f), m3 = fmaxf(sl3, 0.f);
    float w0 = __expf(sl0 - m0), w1 = __expf(sl1 - m1);
    float w2 = __expf(sl2 - m2), w3 = __expf(sl3 - m3);

    float d0 = 0.f, d1 = 0.f, d2 = 0.f, d3 = 0.f;
    for (int base = start; base < end; base += 64) {
        int cnt = min(64, end - base);
        if (lane < cnt) {
            int s = col[base + lane];
            float4 as = *(const float4*)(a_att + s * 8);
            float4 we;
            we.x = __expf(lrelu(as.x + ad.x) - m0);
            we.y = __expf(lrelu(as.y + ad.y) - m1);
            we.z = __expf(lrelu(as.z + ad.z) - m2);
            we.w = __expf(lrelu(as.w + ad.w) - m3);
            *(float4*)(ew + (size_t)(base + lane) * 4) = we;
            d0 += we.x; d1 += we.y; d2 += we.z; d3 += we.w;
        }
    }
#pragma unroll
    for (int off = 32; off; off >>= 1) {
        d0 += __shfl_down(d0, off); d1 += __shfl_down(d1, off);
        d2 += __shfl_down(d2, off); d3 += __shfl_down(d3, off);
    }
    if (lane == 0) {
        *(float4*)(inv_att + n * 8) = make_float4(w0, w1, w2, w3);
        *(float4*)(inv_att + n * 8 + 4) =
            make_float4(1.f / (w0 + d0), 1.f / (w1 + d1), 1.f / (w2 + d2), 1.f / (w3 + d3));
    }
}

// ---------------------------------------------------------------- GAT aggregation, column-split (pass = blockIdx.y)
__global__ __launch_bounds__(256) void gat_pass_kernel(const unsigned short* __restrict__ hb,
                                                       const float* __restrict__ ew,
                                                       const float* __restrict__ inv_att,
                                                       const int* __restrict__ row_start,
                                                       const int* __restrict__ col,
                                                       unsigned short* __restrict__ T) {
    int p = blockIdx.y;
    int wave = threadIdx.x >> 6;
    int lane = threadIdx.x & 63;
    int n = blockIdx.x * 4 + wave;
    int start = row_start[n], end = row_start[n + 1];
    int cb = p * 128 + lane * 2;
    const unsigned short* hg = hb + cb;

    float4 wsf = *(const float4*)(inv_att + n * 8);
    float4 ivf = *(const float4*)(inv_att + n * 8 + 4);
    unsigned int un = *(const unsigned int*)(hg + (size_t)n * HID);
    float hnx = blo(un), hny = bhi(un);
    float ax[4], ay[4];
    ax[0] = wsf.x * hnx; ay[0] = wsf.x * hny;
    ax[1] = wsf.y * hnx; ay[1] = wsf.y * hny;
    ax[2] = wsf.z * hnx; ay[2] = wsf.z * hny;
    ax[3] = wsf.w * hnx; ay[3] = wsf.w * hny;

    int e = start;
    for (; e + 4 <= end; e += 4) {
        int s0 = col[e], s1 = col[e + 1], s2 = col[e + 2], s3 = col[e + 3];
        float4 w0 = *(const float4*)(ew + (size_t)e * 4);
        float4 w1 = *(const float4*)(ew + (size_t)(e + 1) * 4);
        float4 w2 = *(const float4*)(ew + (size_t)(e + 2) * 4);
        float4 w3 = *(const float4*)(ew + (size_t)(e + 3) * 4);
        unsigned int u0 = *(const unsigned int*)(hg + (size_t)s0 * HID);
        unsigned int u1 = *(const unsigned int*)(hg + (size_t)s1 * HID);
        unsigned int u2 = *(const unsigned int*)(hg + (size_t)s2 * HID);
        unsigned int u3 = *(const unsigned int*)(hg + (size_t)s3 * HID);
        float h0x = blo(u0), h0y = bhi(u0);
        float h1x = blo(u1), h1y = bhi(u1);
        float h2x = blo(u2), h2y = bhi(u2);
        float h3x = blo(u3), h3y = bhi(u3);
        ax[0] = fmaf(w0.x, h0x, fmaf(w1.x, h1x, fmaf(w2.x, h2x, fmaf(w3.x, h3x, ax[0]))));
        ay[0] = fmaf(w0.x, h0y, fmaf(w1.x, h1y, fmaf(w2.x, h2y, fmaf(w3.x, h3y, ay[0]))));
        ax[1] = fmaf(w0.y, h0x, fmaf(w1.y, h1x, fmaf(w2.y, h2x, fmaf(w3.y, h3x, ax[1]))));
        ay[1] = fmaf(w0.y, h0y, fmaf(w1.y, h1y, fmaf(w2.y, h2y, fmaf(w3.y, h3y, ay[1]))));
        ax[2] = fmaf(w0.z, h0x, fmaf(w1.z, h1x, fmaf(w2.z, h2x, fmaf(w3.z, h3x, ax[2]))));
        ay[2] = fmaf(w0.z, h0y, fmaf(w1.z, h1y, fmaf(w2.z, h2y, fmaf(w3.z, h3y, ay[2]))));
        ax[3] = fmaf(w0.w, h0x, fmaf(w1.w, h1x, fmaf(w2.w, h2x, fmaf(w3.w, h3x, ax[3]))));
        ay[3] = fmaf(w0.w, h0y, fmaf(w1.w, h1y, fmaf(w2.w, h2y, fmaf(w3.w, h3y, ay[3]))));
    }
    for (; e < end; e++) {
        int s = col[e];
        float4 w = *(const float4*)(ew + (size_t)e * 4);
        unsigned int u = *(const unsigned int*)(hg + (size_t)s * HID);
        float hx = blo(u), hy = bhi(u);
        ax[0] = fmaf(w.x, hx, ax[0]); ay[0] = fmaf(w.x, hy, ay[0]);
        ax[1] = fmaf(w.y, hx, ax[1]); ay[1] = fmaf(w.y, hy, ay[1]);
        ax[2] = fmaf(w.z, hx, ax[2]); ay[2] = fmaf(w.z, hy, ay[2]);
        ax[3] = fmaf(w.w, hx, ax[3]); ay[3] = fmaf(w.w, hy, ay[3]);
    }

    float iv[4] = {ivf.x, ivf.y, ivf.z, ivf.w};
#pragma unroll
    for (int h = 0; h < 4; h++) {
        *(unsigned int*)(T + (size_t)n * (HEADS * HID) + h * HID + cb) =
            pack_bf16x2(ax[h] * iv[h], ay[h] * iv[h]);
    }
}

// ---------------------------------------------------------------- GEMM2: 64x64 tile, dual-slab BK=2x32, fused pool
__global__ __launch_bounds__(256) void gemm2_pool_kernel(const unsigned short* __restrict__ A,
                                                         const unsigned short* __restrict__ Bt,
                                                         const int* __restrict__ batch,
                                                         const float* __restrict__ bias,
                                                         float scale,
                                                         float* __restrict__ pooled,
                                                         int Nn, int K) {
    __shared__ __align__(16) unsigned short As[2][64 * BK];
    __shared__ __align__(16) unsigned short Bs[2][64 * BK];
    __shared__ int bsh[64];

    int tid  = threadIdx.x;
    int wv   = tid >> 6;
    int lane = tid & 63;
    int m0 = blockIdx.y * 64;
    int n0 = blockIdx.x * 64;
    int wm = (wv & 1) * 32;
    int wn = (wv >> 1) * 32;

    if (tid < 64) bsh[tid] = batch[m0 + tid];

    int srow = tid >> 2;
    int scol = (tid & 3) * 8;
    const unsigned short* Ag = A  + (size_t)(m0 + srow) * K + scol;
    const unsigned short* Bg = Bt + (size_t)(n0 + srow) * K + scol;

    int fr = lane & 15;
    int fk = (lane >> 4) * 8;
    f32x4 acc[2][2] = {};

    for (int kt = 0; kt < K; kt += 2 * BK) {
#pragma unroll
        for (int s = 0; s < 2; s++) {
            int ko = kt + s * BK;
            async_copy16(Ag + ko, &As[s][wv * 512]);
            async_copy16(Bg + ko, &Bs[s][wv * 512]);
        }
        __syncthreads();

#pragma unroll
        for (int s = 0; s < 2; s++) {
            short8 af[2], bf[2];
#pragma unroll
            for (int mi = 0; mi < 2; mi++)
                af[mi] = *(const short8*)&As[s][(wm + mi * 16 + fr) * BK + fk];
#pragma unroll
            for (int ni = 0; ni < 2; ni++)
                bf[ni] = *(const short8*)&Bs[s][(wn + ni * 16 + fr) * BK + fk];
#pragma unroll
            for (int mi = 0; mi < 2; mi++)
#pragma unroll
                for (int ni = 0; ni < 2; ni++)
                    acc[mi][ni] = __builtin_amdgcn_mfma_f32_16x16x32_bf16(af[mi], bf[ni], acc[mi][ni], 0, 0, 0);
        }
        __syncthreads();
    }

    int cr = (lane >> 4) * 4;
    int cc = lane & 15;
#pragma unroll
    for (int mi = 0; mi < 2; mi++) {
        int rowb = wm + mi * 16 + cr;
        int b0 = bsh[rowb], b3 = bsh[rowb + 3];
#pragma unroll
        for (int ni = 0; ni < 2; ni++) {
            int gc = n0 + wn + ni * 16 + cc;
            float b = bias[gc];
            float v0 = fmaxf(fmaf(acc[mi][ni][0], scale, b), 0.f);
            float v1 = fmaxf(fmaf(acc[mi][ni][1], scale, b), 0.f);
            float v2 = fmaxf(fmaf(acc[mi][ni][2], scale, b), 0.f);
            float v3 = fmaxf(fmaf(acc[mi][ni][3], scale, b), 0.f);
            if (b0 == b3) {
                atomicAdd(&pooled[b0 * HID + gc], (v0 + v1) + (v2 + v3));
            } else {
                atomicAdd(&pooled[bsh[rowb + 0] * HID + gc], v0);
                atomicAdd(&pooled[bsh[rowb + 1] * HID + gc], v1);
                atomicAdd(&pooled[bsh[rowb + 2] * HID + gc], v2);
                atomicAdd(&pooled[bsh[rowb + 3] * HID + gc], v3);
            }
        }
    }
}

// ---------------------------------------------------------------- head
__device__ __forceinline__ int lower_bound_i(const int* a, int n, int v) {
    int lo = 0, hi = n;
    while (lo < hi) {
        int mid = (lo + hi) >> 1;
        if (a[mid] < v) lo = mid + 1; else hi = mid;
    }
    return lo;
}

__global__ __launch_bounds__(256) void head_kernel(const float* __restrict__ pooled,
                                                   const int* __restrict__ batch,
                                                   const float* __restrict__ head_w,
                                                   const float* __restrict__ head_b,
                                                   float* __restrict__ out) {
    __shared__ float sm[HID];
    int b = blockIdx.x;
    int c = threadIdx.x;
    int lo = lower_bound_i(batch, N_NODES, b);
    int hi = lower_bound_i(batch, N_NODES, b + 1);
    int cnt = hi - lo;
    sm[c] = pooled[b * HID + c] / (float)max(cnt, 1);
    __syncthreads();
    if (c < ACTIONS) {
        float acc = head_b[c];
        for (int k = 0; k < HID; k++) acc = fmaf(sm[k], head_w[k * ACTIONS + c], acc);
        out[b * ACTIONS + c] = acc;
    }
}

// ---------------------------------------------------------------- launcher
extern "C" void kernel_launch(void* const* d_in, const int* in_sizes, int n_in,
                              void* d_out, int out_size, void* d_ws, size_t ws_size,
                              hipStream_t stream) {
    const float* x        = (const float*)d_in[0];
    const int*   ei       = (const int*)d_in[1];
    const int*   batch    = (const int*)d_in[2];
    const float* sage_w_l = (const float*)d_in[3];
    const float* sage_b_l = (const float*)d_in[4];
    const float* sage_w_r = (const float*)d_in[5];
    const float* gat_w    = (const float*)d_in[6];
    const float* att_src  = (const float*)d_in[7];
    const float* att_dst  = (const float*)d_in[8];
    const float* gat_b    = (const float*)d_in[9];
    const float* head_w   = (const float*)d_in[10];
    const float* head_b   = (const float*)d_in[11];
    float* out = (float*)d_out;

    char* w = (char*)d_ws;
    // --- zeroed region (single memset): deg | a_att | pooled ---
    int*   deg    = (int*)w;   w += (size_t)N_NODES * 4;            // 64 KB
    float* a_att  = (float*)w; w += (size_t)N_NODES * 8 * 4;        // 512 KB
    float* pooled = (float*)w; w += (size_t)NBATCH * HID * 4;       // 64 KB
    size_t zero_bytes = (size_t)N_NODES * 4 + (size_t)N_NODES * 8 * 4 + (size_t)NBATCH * HID * 4;
    // --- rest ---
    float* watt   = (float*)w; w += (size_t)8 * HID * 4;
    unsigned short* xlr = (unsigned short*)w; w += (size_t)N_NODES * IN_DIM * 2;
    unsigned short* hb  = (unsigned short*)w; w += (size_t)N_NODES * HID * 2;
    unsigned short* T   = (unsigned short*)w; w += (size_t)N_NODES * HEADS * HID * 2;
    unsigned short* bt1 = (unsigned short*)w; w += (size_t)(2 * HID) * IN_DIM * 2;
    unsigned short* bt2 = (unsigned short*)w; w += (size_t)HID * (HEADS * HID) * 2;
    int* row_start= (int*)w;   w += (size_t)(N_NODES + 64) * 4;
    int* pos      = (int*)w;   w += (size_t)N_NODES * 4;
    int* col      = (int*)w;   w += (size_t)N_EDGES * 4;
    float* ew     = (float*)w; w += (size_t)N_EDGES * 4 * 4;        // per-edge softmax weights (4 heads, f32)
    float* inv_att= (float*)w; w += (size_t)N_NODES * 8 * 4;        // per-node {wself[4], invd[4]}

    hipMemsetAsync(d_ws, 0, zero_bytes, stream);

    setup_kernel<<<NB_SETUP, 256, 0, stream>>>(sage_w_l, sage_w_r, bt1,
                                               gat_w, bt2, att_src, att_dst, watt,
                                               ei, deg);

    scan_kernel<<<1, 256, 0, stream>>>(deg, row_start, pos);

    // xlr = x @ [W_l | W_r] (even y blocks) + CSR fill (odd y blocks)
    gemm1_fill_kernel<<<dim3((2 * HID) / 128, 512), 256, 0, stream>>>(
        x, bt1, xlr, ei, pos, col, 2 * HID, IN_DIM);

    // SAGE aggregation: 2 column passes, each L2-resident (4.2MB slice)
    sage_pass_kernel<<<dim3(N_NODES / 4, 2), 256, 0, stream>>>(
        xlr, row_start, col, sage_b_l, watt, hb, a_att);

    // GAT edge softmax weights (a_att gather only: 512KB working set)
    gat_w_kernel<<<N_NODES / 4, 256, 0, stream>>>(a_att, row_start, col, ew, inv_att);

    // GAT aggregation: 2 column passes, each L2-resident (4.2MB slice)
    gat_pass_kernel<<<dim3(N_NODES / 4, 2), 256, 0, stream>>>(
        hb, ew, inv_att, row_start, col, T);

    gemm2_pool_kernel<<<dim3(HID / 64, N_NODES / 64), 256, 0, stream>>>(
        T, bt2, batch, gat_b, 0.25f, pooled, HID, HEADS * HID);

    head_kernel<<<NBATCH, 256, 0, stream>>>(pooled, batch, head_w, head_b, out);
}

// Round 2
// 263.055 us; speedup vs baseline: 1.0882x; 1.0882x over previous
//
#include <hip/hip_runtime.h>
#include <math.h>

#define N_NODES 16384
#define N_EDGES 262144
#define IN_DIM  512
#define HID     256
#define HEADS   4
#define NBATCH  64
#define ACTIONS 32
#define NEG_SLOPE 0.2f

typedef __attribute__((ext_vector_type(8))) short short8;
typedef __attribute__((ext_vector_type(4))) float f32x4;

__device__ __forceinline__ float lrelu(float v) { return v > 0.f ? v : NEG_SLOPE * v; }

__device__ __forceinline__ unsigned short bf16_rne(float f) {
    union { float f; unsigned int u; } x; x.f = f;
    unsigned int u = x.u;
    unsigned int r = (u + 0x7FFFu + ((u >> 16) & 1u)) >> 16;
    return (unsigned short)r;
}

__device__ __forceinline__ float bf16_to_f32(unsigned short s) {
    union { unsigned int u; float f; } x; x.u = (unsigned int)s << 16;
    return x.f;
}

__device__ __forceinline__ float4 bf4_to_f4(ushort4 u) {
    return make_float4(bf16_to_f32(u.x), bf16_to_f32(u.y), bf16_to_f32(u.z), bf16_to_f32(u.w));
}

__device__ __forceinline__ void async_copy16(const unsigned short* g, unsigned short* l) {
    __builtin_amdgcn_global_load_lds(
        (const __attribute__((address_space(1))) unsigned int*)g,
        (__attribute__((address_space(3))) unsigned int*)l, 16, 0, 0);
}

// ---------------------------------------------------------------- fused setup (+ deg count; deg/pooled zeroed by memset)
#define NB_WLR  1024
#define NB_WSTK 1024
#define NB_WATT 8
#define NB_DEG  1024
#define NB_SETUP (NB_WLR + NB_WSTK + NB_WATT + NB_DEG)

__global__ __launch_bounds__(256) void setup_kernel(
        const float* __restrict__ wl, const float* __restrict__ wr, unsigned short* __restrict__ bt1,
        const float* __restrict__ gat_w, unsigned short* __restrict__ bt2,
        const float* __restrict__ att_src, const float* __restrict__ att_dst, float* __restrict__ watt,
        const int* __restrict__ ei, int* __restrict__ deg) {
    int bid = blockIdx.x, tid = threadIdx.x;
    if (bid < NB_WLR) {
        int idx = bid * 256 + tid;
        int j = idx >> 9;
        int k = idx & 511;
        float v = (j < HID) ? wl[k * HID + j] : wr[k * HID + (j - HID)];
        bt1[idx] = bf16_rne(v);
    } else if (bid < NB_WLR + NB_WSTK) {
        int idx = (bid - NB_WLR) * 256 + tid;
        int c = idx >> 10;
        int r = idx & 1023;
        int h = r >> 8;
        int k = r & 255;
        bt2[idx] = bf16_rne(gat_w[(size_t)k * (HEADS * HID) + h * HID + c]);
    } else if (bid < NB_WLR + NB_WSTK + NB_WATT) {
        int j = bid - NB_WLR - NB_WSTK;
        int c = tid;
        int hh = j & 3;
        const float* att = (j < 4) ? (att_src + hh * HID) : (att_dst + hh * HID);
        float s = 0.f;
        for (int cc = 0; cc < HID; cc++)
            s += gat_w[(size_t)c * (HEADS * HID) + hh * HID + cc] * att[cc];
        watt[j * HID + c] = s;
    } else {
        int e = (bid - NB_WLR - NB_WSTK - NB_WATT) * 256 + tid;
        if (e < N_EDGES) atomicAdd(&deg[ei[N_EDGES + e]], 1);
    }
}

// ---------------------------------------------------------------- CSR scan
__global__ __launch_bounds__(256) void scan_kernel(const int* __restrict__ deg,
                                                   int* __restrict__ row_start,
                                                   int* __restrict__ pos) {
    int t = threadIdx.x;
    int lane = t & 63, wv = t >> 6;
    int base = t * 64;
    int4 buf[16];
    int sum = 0;
#pragma unroll
    for (int i = 0; i < 16; i++) {
        buf[i] = ((const int4*)(deg + base))[i];
        sum += buf[i].x + buf[i].y + buf[i].z + buf[i].w;
    }
    int v = sum;
#pragma unroll
    for (int off = 1; off < 64; off <<= 1) {
        int u = __shfl_up(v, off);
        if (lane >= off) v += u;
    }
    __shared__ int wsum[4];
    if (lane == 63) wsum[wv] = v;
    __syncthreads();
    int wbase = 0;
    for (int w0 = 0; w0 < wv; w0++) wbase += wsum[w0];
    int run = wbase + v - sum;
#pragma unroll
    for (int i = 0; i < 16; i++) {
        int4 b = buf[i];
        int4 o;
        o.x = run; run += b.x;
        o.y = run; run += b.y;
        o.z = run; run += b.z;
        o.w = run; run += b.w;
        ((int4*)(row_start + base))[i] = o;
        ((int4*)(pos + base))[i] = o;
    }
    if (t == 255) row_start[N_NODES] = run;
}

// ---------------------------------------------------------------- CSR fill (separate again — merge into gemm1 regressed)
__global__ void fill_kernel(const int* __restrict__ ei, int* __restrict__ pos,
                            int* __restrict__ col) {
    int e = blockIdx.x * 256 + threadIdx.x;
    if (e < N_EDGES) {
        int s = ei[e];
        int d = ei[N_EDGES + e];
        int p = atomicAdd(&pos[d], 1);
        col[p] = s;
    }
}

// ---------------------------------------------------------------- GEMM1: 64x128 tile, ping-pong double-buffer (2-phase pipeline)
// A register-staged fp32 -> bf16 with T14 issue-early/convert-late split.
#define BK 32

__global__ __launch_bounds__(256) void gemm1_kernel(const float* __restrict__ X,
                                                    const unsigned short* __restrict__ Bt,
                                                    unsigned short* __restrict__ Cb,
                                                    int Nn, int K) {
    __shared__ __align__(16) unsigned short As[2][2][64 * BK];
    __shared__ __align__(16) unsigned short Bs[2][2][128 * BK];

    int tid  = threadIdx.x;
    int wv   = tid >> 6;
    int lane = tid & 63;
    int m0 = blockIdx.y * 64;
    int n0 = blockIdx.x * 128;
    int wm = (wv & 1) * 32;
    int wn = (wv >> 1) * 64;

    int srow = tid >> 2;            // 0..63
    int scol = (tid & 3) * 8;       // 0,8,16,24
    const float*          Xg  = X  + (size_t)(m0 + srow) * K + scol;
    const unsigned short* Bg0 = Bt + (size_t)(n0 + srow) * K + scol;
    const unsigned short* Bg1 = Bt + (size_t)(n0 + 64 + srow) * K + scol;

    int fr = lane & 15;
    int fk = (lane >> 4) * 8;
    f32x4 acc[2][4] = {};
    float4 pa0[2], pa1[2];          // prefetched A fp32 (per slab, two float4 halves)

    // ---- prologue: stage buffer 0 (both slabs)
#pragma unroll
    for (int s = 0; s < 2; s++) {
        int ko = s * BK;
        async_copy16(Bg0 + ko, &Bs[0][s][wv * 512]);
        async_copy16(Bg1 + ko, &Bs[0][s][2048 + wv * 512]);
        pa0[s] = *(const float4*)(Xg + ko);
        pa1[s] = *(const float4*)(Xg + ko + 4);
    }
#pragma unroll
    for (int s = 0; s < 2; s++) {
        short8 p;
        p[0] = (short)bf16_rne(pa0[s].x); p[1] = (short)bf16_rne(pa0[s].y);
        p[2] = (short)bf16_rne(pa0[s].z); p[3] = (short)bf16_rne(pa0[s].w);
        p[4] = (short)bf16_rne(pa1[s].x); p[5] = (short)bf16_rne(pa1[s].y);
        p[6] = (short)bf16_rne(pa1[s].z); p[7] = (short)bf16_rne(pa1[s].w);
        *(short8*)&As[0][s][srow * BK + scol] = p;
    }
    __syncthreads();

    int cur = 0;
    for (int kt = 0; kt < K; kt += 2 * BK) {
        int nxt = kt + 2 * BK;
        bool pf = nxt < K;
        if (pf) {
            // issue next-tile loads NOW (B async -> LDS, A fp32 -> registers)
#pragma unroll
            for (int s = 0; s < 2; s++) {
                int ko = nxt + s * BK;
                async_copy16(Bg0 + ko, &Bs[cur ^ 1][s][wv * 512]);
                async_copy16(Bg1 + ko, &Bs[cur ^ 1][s][2048 + wv * 512]);
                pa0[s] = *(const float4*)(Xg + ko);
                pa1[s] = *(const float4*)(Xg + ko + 4);
            }
        }

        // compute current buffer (MFMA hides the in-flight loads)
#pragma unroll
        for (int s = 0; s < 2; s++) {
            short8 af[2], bf[4];
#pragma unroll
            for (int mi = 0; mi < 2; mi++)
                af[mi] = *(const short8*)&As[cur][s][(wm + mi * 16 + fr) * BK + fk];
#pragma unroll
            for (int ni = 0; ni < 4; ni++)
                bf[ni] = *(const short8*)&Bs[cur][s][(wn + ni * 16 + fr) * BK + fk];
#pragma unroll
            for (int mi = 0; mi < 2; mi++)
#pragma unroll
                for (int ni = 0; ni < 4; ni++)
                    acc[mi][ni] = __builtin_amdgcn_mfma_f32_16x16x32_bf16(af[mi], bf[ni], acc[mi][ni], 0, 0, 0);
        }

        if (pf) {
            // convert + LDS-write late: vmcnt wait on pa lands after the MFMAs
#pragma unroll
            for (int s = 0; s < 2; s++) {
                short8 p;
                p[0] = (short)bf16_rne(pa0[s].x); p[1] = (short)bf16_rne(pa0[s].y);
                p[2] = (short)bf16_rne(pa0[s].z); p[3] = (short)bf16_rne(pa0[s].w);
                p[4] = (short)bf16_rne(pa1[s].x); p[5] = (short)bf16_rne(pa1[s].y);
                p[6] = (short)bf16_rne(pa1[s].z); p[7] = (short)bf16_rne(pa1[s].w);
                *(short8*)&As[cur ^ 1][s][srow * BK + scol] = p;
            }
        }
        __syncthreads();
        cur ^= 1;
    }

    int cr = (lane >> 4) * 4;
    int cc = lane & 15;
#pragma unroll
    for (int mi = 0; mi < 2; mi++) {
#pragma unroll
        for (int ni = 0; ni < 4; ni++) {
            int gc = n0 + wn + ni * 16 + cc;
#pragma unroll
            for (int r = 0; r < 4; r++) {
                int gr = m0 + wm + mi * 16 + cr + r;
                Cb[(size_t)gr * Nn + gc] = bf16_rne(acc[mi][ni][r]);
            }
        }
    }
}

// ---------------------------------------------------------------- GEMM2: 64x64 tile, ping-pong double-buffer, fused pool
__global__ __launch_bounds__(256) void gemm2_pool_kernel(const unsigned short* __restrict__ A,
                                                         const unsigned short* __restrict__ Bt,
                                                         const int* __restrict__ batch,
                                                         const float* __restrict__ bias,
                                                         float scale,
                                                         float* __restrict__ pooled,
                                                         int Nn, int K) {
    __shared__ __align__(16) unsigned short As[2][2][64 * BK];
    __shared__ __align__(16) unsigned short Bs[2][2][64 * BK];
    __shared__ int bsh[64];

    int tid  = threadIdx.x;
    int wv   = tid >> 6;
    int lane = tid & 63;
    int m0 = blockIdx.y * 64;
    int n0 = blockIdx.x * 64;
    int wm = (wv & 1) * 32;
    int wn = (wv >> 1) * 32;

    if (tid < 64) bsh[tid] = batch[m0 + tid];

    int srow = tid >> 2;
    int scol = (tid & 3) * 8;
    const unsigned short* Ag = A  + (size_t)(m0 + srow) * K + scol;
    const unsigned short* Bg = Bt + (size_t)(n0 + srow) * K + scol;

    int fr = lane & 15;
    int fk = (lane >> 4) * 8;
    f32x4 acc[2][2] = {};

    // ---- prologue: stage buffer 0
#pragma unroll
    for (int s = 0; s < 2; s++) {
        int ko = s * BK;
        async_copy16(Ag + ko, &As[0][s][wv * 512]);
        async_copy16(Bg + ko, &Bs[0][s][wv * 512]);
    }
    __syncthreads();

    int cur = 0;
    for (int kt = 0; kt < K; kt += 2 * BK) {
        int nxt = kt + 2 * BK;
        bool pf = nxt < K;
        if (pf) {
#pragma unroll
            for (int s = 0; s < 2; s++) {
                int ko = nxt + s * BK;
                async_copy16(Ag + ko, &As[cur ^ 1][s][wv * 512]);
                async_copy16(Bg + ko, &Bs[cur ^ 1][s][wv * 512]);
            }
        }

#pragma unroll
        for (int s = 0; s < 2; s++) {
            short8 af[2], bf[2];
#pragma unroll
            for (int mi = 0; mi < 2; mi++)
                af[mi] = *(const short8*)&As[cur][s][(wm + mi * 16 + fr) * BK + fk];
#pragma unroll
            for (int ni = 0; ni < 2; ni++)
                bf[ni] = *(const short8*)&Bs[cur][s][(wn + ni * 16 + fr) * BK + fk];
#pragma unroll
            for (int mi = 0; mi < 2; mi++)
#pragma unroll
                for (int ni = 0; ni < 2; ni++)
                    acc[mi][ni] = __builtin_amdgcn_mfma_f32_16x16x32_bf16(af[mi], bf[ni], acc[mi][ni], 0, 0, 0);
        }
        __syncthreads();
        cur ^= 1;
    }

    int cr = (lane >> 4) * 4;
    int cc = lane & 15;
#pragma unroll
    for (int mi = 0; mi < 2; mi++) {
        int rowb = wm + mi * 16 + cr;
        int b0 = bsh[rowb], b3 = bsh[rowb + 3];
#pragma unroll
        for (int ni = 0; ni < 2; ni++) {
            int gc = n0 + wn + ni * 16 + cc;
            float b = bias[gc];
            float v0 = fmaxf(fmaf(acc[mi][ni][0], scale, b), 0.f);
            float v1 = fmaxf(fmaf(acc[mi][ni][1], scale, b), 0.f);
            float v2 = fmaxf(fmaf(acc[mi][ni][2], scale, b), 0.f);
            float v3 = fmaxf(fmaf(acc[mi][ni][3], scale, b), 0.f);
            if (b0 == b3) {
                atomicAdd(&pooled[b0 * HID + gc], (v0 + v1) + (v2 + v3));
            } else {
                atomicAdd(&pooled[bsh[rowb + 0] * HID + gc], v0);
                atomicAdd(&pooled[bsh[rowb + 1] * HID + gc], v1);
                atomicAdd(&pooled[bsh[rowb + 2] * HID + gc], v2);
                atomicAdd(&pooled[bsh[rowb + 3] * HID + gc], v3);
            }
        }
    }
}

// ---------------------------------------------------------------- SAGE aggregation (round-0 proven 4x unroll)
__global__ __launch_bounds__(256) void sage_agg_kernel(const unsigned short* __restrict__ xlr,
                                                       const int* __restrict__ row_start,
                                                       const int* __restrict__ col,
                                                       const float* __restrict__ b_l,
                                                       const float* __restrict__ watt,
                                                       unsigned short* __restrict__ hb,
                                                       float* __restrict__ a_att) {
    __shared__ float watt_s[8 * HID];
    for (int i = threadIdx.x; i < 8 * HID; i += 256) watt_s[i] = watt[i];
    __syncthreads();

    int wave = threadIdx.x >> 6;
    int lane = threadIdx.x & 63;
    int n = blockIdx.x * 4 + wave;
    int start = row_start[n], end = row_start[n + 1];
    int c0 = lane * 4;

    float4 acc = make_float4(0.f, 0.f, 0.f, 0.f);
    int e = start;
    for (; e + 4 <= end; e += 4) {
        int s0 = col[e], s1 = col[e + 1], s2 = col[e + 2], s3 = col[e + 3];
        ushort4 u0 = *(const ushort4*)(xlr + (size_t)s0 * IN_DIM + c0);
        ushort4 u1 = *(const ushort4*)(xlr + (size_t)s1 * IN_DIM + c0);
        ushort4 u2 = *(const ushort4*)(xlr + (size_t)s2 * IN_DIM + c0);
        ushort4 u3 = *(const ushort4*)(xlr + (size_t)s3 * IN_DIM + c0);
        float4 v0 = bf4_to_f4(u0), v1 = bf4_to_f4(u1), v2 = bf4_to_f4(u2), v3 = bf4_to_f4(u3);
        acc.x += (v0.x + v1.x) + (v2.x + v3.x);
        acc.y += (v0.y + v1.y) + (v2.y + v3.y);
        acc.z += (v0.z + v1.z) + (v2.z + v3.z);
        acc.w += (v0.w + v1.w) + (v2.w + v3.w);
    }
    for (; e < end; e++) {
        int s = col[e];
        float4 v = bf4_to_f4(*(const ushort4*)(xlr + (size_t)s * IN_DIM + c0));
        acc.x += v.x; acc.y += v.y; acc.z += v.z; acc.w += v.w;
    }
    float inv = 1.f / (float)max(end - start, 1);
    float4 xr = bf4_to_f4(*(const ushort4*)(xlr + (size_t)n * IN_DIM + HID + c0));
    float4 bl = *(const float4*)(b_l + c0);
    float4 hv;
    hv.x = fmaxf(fmaf(acc.x, inv, bl.x + xr.x), 0.f);
    hv.y = fmaxf(fmaf(acc.y, inv, bl.y + xr.y), 0.f);
    hv.z = fmaxf(fmaf(acc.z, inv, bl.z + xr.z), 0.f);
    hv.w = fmaxf(fmaf(acc.w, inv, bl.w + xr.w), 0.f);
    ushort4 ho;
    ho.x = bf16_rne(hv.x); ho.y = bf16_rne(hv.y); ho.z = bf16_rne(hv.z); ho.w = bf16_rne(hv.w);
    *(ushort4*)(hb + (size_t)n * HID + c0) = ho;

    float p[8];
#pragma unroll
    for (int j = 0; j < 8; j++) {
        float4 wt = *(const float4*)&watt_s[j * HID + c0];
        p[j] = hv.x * wt.x + hv.y * wt.y + hv.z * wt.z + hv.w * wt.w;
    }
#pragma unroll
    for (int off = 32; off; off >>= 1)
#pragma unroll
        for (int j = 0; j < 8; j++) p[j] += __shfl_down(p[j], off);
    if (lane == 0) {
#pragma unroll
        for (int j = 0; j < 8; j++) a_att[n * 8 + j] = p[j];
    }
}

// ---------------------------------------------------------------- GAT: single-sweep softmax + aggregation (round-0 proven)
__global__ __launch_bounds__(256) void gat_agg_kernel(const unsigned short* __restrict__ hb,
                                                      const float* __restrict__ a_att,
                                                      const int* __restrict__ row_start,
                                                      const int* __restrict__ col,
                                                      unsigned short* __restrict__ T) {
    __shared__ __align__(16) float w_s[4][64 * 4];
    int wave = threadIdx.x >> 6;
    int lane = threadIdx.x & 63;
    int n = blockIdx.x * 4 + wave;
    int start = row_start[n], end = row_start[n + 1];

    float4 an = *(const float4*)(a_att + n * 8);
    float4 ad = *(const float4*)(a_att + n * 8 + 4);
    float adst[4] = {ad.x, ad.y, ad.z, ad.w};
    float selfl[4] = {lrelu(an.x + ad.x), lrelu(an.y + ad.y), lrelu(an.z + ad.z), lrelu(an.w + ad.w)};
    float m[4], wself[4];
#pragma unroll
    for (int hh = 0; hh < 4; hh++) {
        m[hh] = fmaxf(selfl[hh], 0.f);
        wself[hh] = __expf(selfl[hh] - m[hh]);
    }

    int c0 = lane * 4;
    float4 hn = bf4_to_f4(*(const ushort4*)(hb + (size_t)n * HID + c0));
    float4 acc[4];
#pragma unroll
    for (int hh = 0; hh < 4; hh++)
        acc[hh] = make_float4(wself[hh] * hn.x, wself[hh] * hn.y, wself[hh] * hn.z, wself[hh] * hn.w);

    float dpart[4] = {0.f, 0.f, 0.f, 0.f};

    for (int base = start; base < end; base += 64) {
        int cnt = min(64, end - base);
        if (lane < cnt) {
            int s = col[base + lane];
            float4 as = *(const float4*)(a_att + s * 8);
            float4 wv;
            wv.x = __expf(lrelu(as.x + adst[0]) - m[0]);
            wv.y = __expf(lrelu(as.y + adst[1]) - m[1]);
            wv.z = __expf(lrelu(as.z + adst[2]) - m[2]);
            wv.w = __expf(lrelu(as.w + adst[3]) - m[3]);
            *(float4*)&w_s[wave][lane * 4] = wv;
            dpart[0] += wv.x; dpart[1] += wv.y; dpart[2] += wv.z; dpart[3] += wv.w;
        }
        __builtin_amdgcn_wave_barrier();

        int i = 0;
        for (; i + 2 <= cnt; i += 2) {
            int s0 = col[base + i], s1 = col[base + i + 1];
            float4 w0 = *(const float4*)&w_s[wave][i * 4];
            float4 w1 = *(const float4*)&w_s[wave][(i + 1) * 4];
            ushort4 u0 = *(const ushort4*)(hb + (size_t)s0 * HID + c0);
            ushort4 u1 = *(const ushort4*)(hb + (size_t)s1 * HID + c0);
            float4 h0 = bf4_to_f4(u0), h1 = bf4_to_f4(u1);
            float wr0[4] = {w0.x, w0.y, w0.z, w0.w};
            float wr1[4] = {w1.x, w1.y, w1.z, w1.w};
#pragma unroll
            for (int hh = 0; hh < 4; hh++) {
                acc[hh].x = fmaf(wr0[hh], h0.x, fmaf(wr1[hh], h1.x, acc[hh].x));
                acc[hh].y = fmaf(wr0[hh], h0.y, fmaf(wr1[hh], h1.y, acc[hh].y));
                acc[hh].z = fmaf(wr0[hh], h0.z, fmaf(wr1[hh], h1.z, acc[hh].z));
                acc[hh].w = fmaf(wr0[hh], h0.w, fmaf(wr1[hh], h1.w, acc[hh].w));
            }
        }
        if (i < cnt) {
            int s0 = col[base + i];
            float4 w0 = *(const float4*)&w_s[wave][i * 4];
            float4 h0 = bf4_to_f4(*(const ushort4*)(hb + (size_t)s0 * HID + c0));
            float wr0[4] = {w0.x, w0.y, w0.z, w0.w};
#pragma unroll
            for (int hh = 0; hh < 4; hh++) {
                acc[hh].x = fmaf(wr0[hh], h0.x, acc[hh].x);
                acc[hh].y = fmaf(wr0[hh], h0.y, acc[hh].y);
                acc[hh].z = fmaf(wr0[hh], h0.z, acc[hh].z);
                acc[hh].w = fmaf(wr0[hh], h0.w, acc[hh].w);
            }
        }
        __builtin_amdgcn_wave_barrier();
    }

#pragma unroll
    for (int off = 32; off; off >>= 1)
#pragma unroll
        for (int hh = 0; hh < 4; hh++) dpart[hh] += __shfl_down(dpart[hh], off);
    float invd[4];
#pragma unroll
    for (int hh = 0; hh < 4; hh++)
        invd[hh] = 1.f / (__shfl(dpart[hh], 0) + wself[hh]);

#pragma unroll
    for (int hh = 0; hh < 4; hh++) {
        ushort4 o;
        o.x = bf16_rne(acc[hh].x * invd[hh]); o.y = bf16_rne(acc[hh].y * invd[hh]);
        o.z = bf16_rne(acc[hh].z * invd[hh]); o.w = bf16_rne(acc[hh].w * invd[hh]);
        *(ushort4*)(T + (size_t)n * (HEADS * HID) + hh * HID + c0) = o;
    }
}

// ---------------------------------------------------------------- head
__device__ __forceinline__ int lower_bound_i(const int* a, int n, int v) {
    int lo = 0, hi = n;
    while (lo < hi) {
        int mid = (lo + hi) >> 1;
        if (a[mid] < v) lo = mid + 1; else hi = mid;
    }
    return lo;
}

__global__ __launch_bounds__(256) void head_kernel(const float* __restrict__ pooled,
                                                   const int* __restrict__ batch,
                                                   const float* __restrict__ head_w,
                                                   const float* __restrict__ head_b,
                                                   float* __restrict__ out) {
    __shared__ float sm[HID];
    int b = blockIdx.x;
    int c = threadIdx.x;
    int lo = lower_bound_i(batch, N_NODES, b);
    int hi = lower_bound_i(batch, N_NODES, b + 1);
    int cnt = hi - lo;
    sm[c] = pooled[b * HID + c] / (float)max(cnt, 1);
    __syncthreads();
    if (c < ACTIONS) {
        float acc = head_b[c];
        for (int k = 0; k < HID; k++) acc = fmaf(sm[k], head_w[k * ACTIONS + c], acc);
        out[b * ACTIONS + c] = acc;
    }
}

// ---------------------------------------------------------------- launcher
extern "C" void kernel_launch(void* const* d_in, const int* in_sizes, int n_in,
                              void* d_out, int out_size, void* d_ws, size_t ws_size,
                              hipStream_t stream) {
    const float* x        = (const float*)d_in[0];
    const int*   ei       = (const int*)d_in[1];
    const int*   batch    = (const int*)d_in[2];
    const float* sage_w_l = (const float*)d_in[3];
    const float* sage_b_l = (const float*)d_in[4];
    const float* sage_w_r = (const float*)d_in[5];
    const float* gat_w    = (const float*)d_in[6];
    const float* att_src  = (const float*)d_in[7];
    const float* att_dst  = (const float*)d_in[8];
    const float* gat_b    = (const float*)d_in[9];
    const float* head_w   = (const float*)d_in[10];
    const float* head_b   = (const float*)d_in[11];
    float* out = (float*)d_out;

    char* w = (char*)d_ws;
    // --- zeroed region (single memset): deg | pooled ---
    int*   deg    = (int*)w;   w += (size_t)N_NODES * 4;            // 64 KB
    float* pooled = (float*)w; w += (size_t)NBATCH * HID * 4;       // 64 KB
    size_t zero_bytes = (size_t)N_NODES * 4 + (size_t)NBATCH * HID * 4;
    // --- rest ---
    float* a_att  = (float*)w; w += (size_t)N_NODES * 8 * 4;
    float* watt   = (float*)w; w += (size_t)8 * HID * 4;
    unsigned short* xlr = (unsigned short*)w; w += (size_t)N_NODES * IN_DIM * 2;
    unsigned short* hb  = (unsigned short*)w; w += (size_t)N_NODES * HID * 2;
    unsigned short* T   = (unsigned short*)w; w += (size_t)N_NODES * HEADS * HID * 2;
    unsigned short* bt1 = (unsigned short*)w; w += (size_t)(2 * HID) * IN_DIM * 2;
    unsigned short* bt2 = (unsigned short*)w; w += (size_t)HID * (HEADS * HID) * 2;
    int* row_start= (int*)w;   w += (size_t)(N_NODES + 64) * 4;
    int* pos      = (int*)w;   w += (size_t)N_NODES * 4;
    int* col      = (int*)w;   w += (size_t)N_EDGES * 4;

    hipMemsetAsync(d_ws, 0, zero_bytes, stream);

    setup_kernel<<<NB_SETUP, 256, 0, stream>>>(sage_w_l, sage_w_r, bt1,
                                               gat_w, bt2, att_src, att_dst, watt,
                                               ei, deg);

    scan_kernel<<<1, 256, 0, stream>>>(deg, row_start, pos);
    fill_kernel<<<N_EDGES / 256, 256, 0, stream>>>(ei, pos, col);

    // xlr = x @ [W_l | W_r]  (pipelined, fused bf16 conversion of A)
    gemm1_kernel<<<dim3((2 * HID) / 128, N_NODES / 64), 256, 0, stream>>>(
        x, bt1, xlr, 2 * HID, IN_DIM);

    sage_agg_kernel<<<N_NODES / 4, 256, 0, stream>>>(xlr, row_start, col, sage_b_l, watt, hb, a_att);

    gat_agg_kernel<<<N_NODES / 4, 256, 0, stream>>>(hb, a_att, row_start, col, T);

    gemm2_pool_kernel<<<dim3(HID / 64, N_NODES / 64), 256, 0, stream>>>(
        T, bt2, batch, gat_b, 0.25f, pooled, HID, HEADS * HID);

    head_kernel<<<NBATCH, 256, 0, stream>>>(pooled, batch, head_w, head_b, out);
}